// Round 4
// baseline (121.467 us; speedup 1.0000x reference)
//
#include <hip/hip_runtime.h>

// LinearAttention: B=4, H=8, L=4096, D=64, fp32 in/out.
// out = elu1(Q) @ KV / (elu1(Q)·Ksum + eps),  KV = elu1(K)^T @ V  (L-scalings cancel).
//
// K1 : 1024 blocks (32 heads x 32 chunks of 128 rows). TRANSPOSED ownership:
//      lane l accumulates KV row d=l (64 v-cols in 32 f2 regs). K: one coalesced
//      dword per row, fmap ONCE per element. V row is wave-uniform -> scalar
//      loads feeding v_pk_fma_f32. No LDS/barriers in hot loop; one-time
//      cross-wave LDS reduce (stride-68 padding), partial -> private ws slot.
// K1r: 160 blocks reduce 32 partials/head.
// K2 : 512 blocks (32 heads x 16 tiles of 256 rows), thread t owns row t.
//      KV rows are block-uniform -> scalar loads; no LDS, no barriers.

#define LSEQ   4096
#define DDIM   64
#define NHEAD  32
#define K1CH   32
#define K1ROWS (LSEQ / K1CH)          // 128 rows per K1 block
#define WSPH   (DDIM * DDIM + DDIM)   // 4160 floats per partial / head
#define WSPH4  (WSPH / 4)             // 1040 float4
#define RSTRIDE 68                    // padded LDS row stride (floats)

typedef float f2 __attribute__((ext_vector_type(2)));

__device__ __forceinline__ float fmap(float x) {
    return x > 0.0f ? (x + 1.0f) : __expf(x);   // elu(x)+1
}
__device__ __forceinline__ f2 pkfma(f2 a, f2 b, f2 c) {
    return __builtin_elementwise_fma(a, b, c);   // -> v_pk_fma_f32
}

// ---------------- Kernel 1: partial KV[64][64] + Ksum[64] per (head,chunk) ----
__global__ __launch_bounds__(256) void la_kv_kernel(
    const float* __restrict__ Kg, const float* __restrict__ Vg,
    float* __restrict__ ws)
{
    __shared__ float red[DDIM * RSTRIDE];   // 64 rows, padded stride
    __shared__ float kred[DDIM];

    const int t    = threadIdx.x;
    const int wave = t >> 6;
    const int lane = t & 63;

    const int bh    = blockIdx.x / K1CH;
    const int chunk = blockIdx.x % K1CH;
    const size_t base = (size_t)bh * LSEQ * DDIM + (size_t)chunk * K1ROWS * DDIM
                      + (size_t)wave * 32 * DDIM;   // 32 rows per wave
    const float* Kp = Kg + base;
    const float* Vp = Vg + base;

    f2 acc[32];                 // KV row d=lane, 64 v-cols
    float ksum = 0.0f;
#pragma unroll
    for (int j = 0; j < 32; ++j) acc[j] = (f2)(0.0f);

#pragma unroll 1
    for (int g = 0; g < 4; ++g) {                 // 4 groups of 8 rows
        // issue the 8 K loads for this group up front (coalesced dwords)
        float kk[8];
#pragma unroll
        for (int r = 0; r < 8; ++r)
            kk[r] = Kp[(g * 8 + r) * DDIM + lane];
#pragma unroll
        for (int r = 0; r < 8; ++r) {
            const float kf = fmap(kk[r]);
            ksum += kf;
            const f2 kf2 = {kf, kf};
            const float4* vr = (const float4*)(Vp + (size_t)(g * 8 + r) * DDIM);
#pragma unroll
            for (int j = 0; j < 16; ++j) {
                const float4 v4 = vr[j];          // wave-uniform -> s_load
                acc[2 * j]     = pkfma(kf2, (f2){v4.x, v4.y}, acc[2 * j]);
                acc[2 * j + 1] = pkfma(kf2, (f2){v4.z, v4.w}, acc[2 * j + 1]);
            }
        }
    }

    // one-time cross-wave reduce (sequential wave turns)
    for (int w = 0; w < 4; ++w) {
        __syncthreads();
        if (wave == w) {
            float* p = red + lane * RSTRIDE;
            if (w == 0) {
#pragma unroll
                for (int j = 0; j < 16; ++j)
                    *(float4*)(p + j * 4) = make_float4(acc[2*j].x, acc[2*j].y,
                                                        acc[2*j+1].x, acc[2*j+1].y);
                kred[lane] = ksum;
            } else {
#pragma unroll
                for (int j = 0; j < 16; ++j) {
                    float4 x = *(const float4*)(p + j * 4);
                    x.x += acc[2*j].x;   x.y += acc[2*j].y;
                    x.z += acc[2*j+1].x; x.w += acc[2*j+1].y;
                    *(float4*)(p + j * 4) = x;
                }
                kred[lane] += ksum;
            }
        }
    }
    __syncthreads();

    // coalesced store of the block's partial into its PRIVATE slot
    float4* dst = (float4*)(ws + (size_t)blockIdx.x * WSPH);
    for (int i = t; i < 1024; i += 256) {
        const int row = i >> 4, c4 = i & 15;
        dst[i] = *(const float4*)(red + row * RSTRIDE + c4 * 4);
    }
    if (t < 16)
        dst[1024 + t] = *(const float4*)(kred + t * 4);
}

// ---------------- Kernel 1r: reduce 32 partials per head -> final KV+Ksum ----
__global__ __launch_bounds__(256) void la_reduce_kernel(
    const float* __restrict__ ws, float* __restrict__ kvout)
{
    const int h   = blockIdx.x / 5;
    const int seg = blockIdx.x % 5;
    const int t   = threadIdx.x;
    if (t >= 208) return;
    const int i4 = seg * 208 + t;

    const float4* base = (const float4*)(ws + (size_t)h * K1CH * WSPH) + i4;
    float4 acc = make_float4(0.f, 0.f, 0.f, 0.f);
#pragma unroll 8
    for (int p = 0; p < K1CH; ++p) {
        const float4 x = base[(size_t)p * WSPH4];
        acc.x += x.x; acc.y += x.y; acc.z += x.z; acc.w += x.w;
    }
    ((float4*)(kvout + (size_t)h * WSPH))[i4] = acc;
}

// ---------------- Kernel 2: out = (Qf @ KV) / (Qf·Ksum + eps) -----------------
// grid = NHEAD*16 blocks, 256 threads; thread t owns output row t of the tile.
__global__ __launch_bounds__(256) void la_out_kernel(
    const float* __restrict__ Qg, const float* __restrict__ kvin,
    float* __restrict__ out)
{
    const int t    = threadIdx.x;
    const int bh   = blockIdx.x >> 4;
    const int tile = blockIdx.x & 15;
    const size_t rowbase = (size_t)bh * LSEQ * DDIM
                         + ((size_t)tile * 256 + t) * DDIM;
    const float* qrow = Qg + rowbase;
    float*       orow = out + rowbase;
    const float* KV = kvin + (size_t)bh * WSPH;   // block-uniform
    const float* Ks = KV + DDIM * DDIM;

    f2 acc[32];
    float den = 0.0f;
#pragma unroll
    for (int j = 0; j < 32; ++j) acc[j] = (f2)(0.0f);

#pragma unroll 1
    for (int d4 = 0; d4 < 16; ++d4) {
        float4 q4 = *(const float4*)(qrow + d4 * 4);   // per-lane, 16B
        q4.x = fmap(q4.x); q4.y = fmap(q4.y); q4.z = fmap(q4.z); q4.w = fmap(q4.w);
        const float4 ks4 = *(const float4*)(Ks + d4 * 4);   // uniform
        den += q4.x * ks4.x + q4.y * ks4.y + q4.z * ks4.z + q4.w * ks4.w;
        const float qa[4] = {q4.x, q4.y, q4.z, q4.w};
#pragma unroll
        for (int i = 0; i < 4; ++i) {
            const f2 qd = {qa[i], qa[i]};
            const float4* kvr = (const float4*)(KV + (size_t)(d4 * 4 + i) * DDIM);
#pragma unroll
            for (int j = 0; j < 16; ++j) {
                const float4 kv4 = kvr[j];        // uniform -> s_load
                acc[2 * j]     = pkfma(qd, (f2){kv4.x, kv4.y}, acc[2 * j]);
                acc[2 * j + 1] = pkfma(qd, (f2){kv4.z, kv4.w}, acc[2 * j + 1]);
            }
        }
    }

    const float z = 1.0f / (den + 1e-6f);
#pragma unroll
    for (int j = 0; j < 16; ++j) {
        const float4 o = make_float4(acc[2*j].x * z, acc[2*j].y * z,
                                     acc[2*j+1].x * z, acc[2*j+1].y * z);
        *(float4*)(orow + j * 4) = o;
    }
}

extern "C" void kernel_launch(void* const* d_in, const int* in_sizes, int n_in,
                              void* d_out, int out_size, void* d_ws, size_t ws_size,
                              hipStream_t stream) {
    const float* q = (const float*)d_in[0];
    const float* k = (const float*)d_in[1];
    const float* v = (const float*)d_in[2];
    float* o  = (float*)d_out;
    float* ws = (float*)d_ws;
    float* kvfinal = ws + (size_t)NHEAD * K1CH * WSPH;

    hipLaunchKernelGGL(la_kv_kernel, dim3(NHEAD * K1CH), dim3(256), 0, stream,
                       k, v, ws);
    hipLaunchKernelGGL(la_reduce_kernel, dim3(NHEAD * 5), dim3(256), 0, stream,
                       ws, kvfinal);
    hipLaunchKernelGGL(la_out_kernel, dim3(NHEAD * 16), dim3(256), 0, stream,
                       q, kvfinal, o);
}

// Round 5
// 59.056 us; speedup vs baseline: 2.0568x; 2.0568x over previous
//
#include <hip/hip_runtime.h>

// LinearAttention: B=4, H=8, L=4096, D=64, fp32 in/out.
// out = elu1(Q) @ KV / (elu1(Q)·Ksum + eps),  KV = elu1(K)^T @ V  (L-scalings cancel).
//
// K1 : 1024 blocks (32 heads x 32 chunks of 128 rows). LDS-staged 16-row tiles,
//      alternating buffers, T14 split (issue next tile's global loads BEFORE
//      compute, LDS-write after; 1 barrier/tile). fmap applied once at staging.
//      Lane (dq,vq) owns an 8d x 8v patch; all LDS reads are 8-way-broadcast
//      conflict-free. Packed v_pk_fma_f32 compute. Cross-wave reduce in LDS
//      (chunk-XOR swizzled), partial -> private ws slot.
// K1r: 160 blocks reduce 32 partials/head.
// K2 : 1024 blocks (32 heads x 32 tiles of 128 rows). Qf (fmapped) staged in
//      LDS at row pitch 84 (bank-spread for the rows rg+32k access pattern),
//      KV+Ksum in LDS (broadcast reads). den pass, then register-blocked
//      packed GEMM; lane owns rows {rg,rg+32,rg+64,rg+96} x 8 cols.

#define LSEQ   4096
#define DDIM   64
#define NHEAD  32
#define K1CH   32
#define K1ROWS (LSEQ / K1CH)          // 128 rows per K1 block
#define T1ROWS 16                     // staged tile rows (K1)
#define NT1    (K1ROWS / T1ROWS)      // 8 tiles
#define WSPH   (DDIM * DDIM + DDIM)   // 4160 floats per partial / head
#define WSPH4  (WSPH / 4)             // 1040 float4
#define ST2    84                     // K2 Qf LDS row pitch (floats)

typedef float f2 __attribute__((ext_vector_type(2)));

__device__ __forceinline__ float fmap(float x) {
    return x > 0.0f ? (x + 1.0f) : __expf(x);   // elu(x)+1
}
__device__ __forceinline__ float4 fmap4(float4 v) {
    v.x = fmap(v.x); v.y = fmap(v.y); v.z = fmap(v.z); v.w = fmap(v.w);
    return v;
}
__device__ __forceinline__ f2 pkfma(f2 a, f2 b, f2 c) {
    return __builtin_elementwise_fma(a, b, c);   // -> v_pk_fma_f32
}

// ---------------- Kernel 1: partial KV[64][64] + Ksum[64] per (head,chunk) ----
__global__ __launch_bounds__(256) void la_kv_kernel(
    const float* __restrict__ Kg, const float* __restrict__ Vg,
    float* __restrict__ ws)
{
    __shared__ float kst[2][T1ROWS * DDIM];
    __shared__ float vst[2][T1ROWS * DDIM];
    __shared__ float red[DDIM * DDIM];
    __shared__ float kred[DDIM];

    const int t    = threadIdx.x;
    const int wave = t >> 6;
    const int lane = t & 63;
    const int dq   = lane >> 3;
    const int vq   = lane & 7;

    const int bh    = blockIdx.x / K1CH;
    const int chunk = blockIdx.x % K1CH;
    const size_t base = (size_t)bh * LSEQ * DDIM + (size_t)chunk * K1ROWS * DDIM;
    const float4* Kb4 = (const float4*)(Kg + base);
    const float4* Vb4 = (const float4*)(Vg + base);

    // stage tile 0
    ((float4*)kst[0])[t] = fmap4(Kb4[t]);
    ((float4*)vst[0])[t] = Vb4[t];
    __syncthreads();

    f2 acc[8][4];               // 8 d-rows x 8 v-cols (4 f2)
    f2 ksum2[4] = {(f2)(0.f), (f2)(0.f), (f2)(0.f), (f2)(0.f)};
#pragma unroll
    for (int i = 0; i < 8; ++i)
#pragma unroll
        for (int j = 0; j < 4; ++j) acc[i][j] = (f2)(0.0f);

#pragma unroll 1
    for (int tl = 0; tl < NT1; ++tl) {
        const int cur = tl & 1;
        const bool pre = (tl + 1 < NT1);
        float4 kx, vx;
        if (pre) {                       // issue next tile's loads EARLY (T14)
            kx = Kb4[(tl + 1) * 256 + t];
            vx = Vb4[(tl + 1) * 256 + t];
        }

        // compute 4 rows of current tile (rows wave*4 .. +3)
#pragma unroll
        for (int r = 0; r < 4; ++r) {
            const int l = wave * 4 + r;
            const float4 ka = *(const float4*)(kst[cur] + l * DDIM + dq * 8);
            const float4 kb = *(const float4*)(kst[cur] + l * DDIM + dq * 8 + 4);
            const float4 va = *(const float4*)(vst[cur] + l * DDIM + vq * 4);
            const float4 vb = *(const float4*)(vst[cur] + l * DDIM + 32 + vq * 4);
            const float kk[8] = {ka.x, ka.y, ka.z, ka.w, kb.x, kb.y, kb.z, kb.w};
            const f2 vv[4] = {{va.x, va.y}, {va.z, va.w}, {vb.x, vb.y}, {vb.z, vb.w}};
            ksum2[0] += (f2){kk[0], kk[1]};
            ksum2[1] += (f2){kk[2], kk[3]};
            ksum2[2] += (f2){kk[4], kk[5]};
            ksum2[3] += (f2){kk[6], kk[7]};
#pragma unroll
            for (int i = 0; i < 8; ++i) {
                const f2 ki = {kk[i], kk[i]};
#pragma unroll
                for (int j = 0; j < 4; ++j)
                    acc[i][j] = pkfma(ki, vv[j], acc[i][j]);
            }
        }

        if (pre) {                       // LDS-write AFTER compute
            ((float4*)kst[cur ^ 1])[t] = fmap4(kx);
            ((float4*)vst[cur ^ 1])[t] = vx;
        }
        __syncthreads();
    }

    // cross-wave reduce in LDS, chunk-XOR swizzle (phys chunk = vq^dq) so the
    // 8 dq-lanes of a fixed logical chunk hit 8 different bank groups.
    float4* red4 = (float4*)red;
    for (int w = 0; w < 4; ++w) {
        __syncthreads();
        if (wave == w) {
            const int pj = vq ^ dq;
#pragma unroll
            for (int i = 0; i < 8; ++i) {
                const int d = dq * 8 + i;
                float4 lo = make_float4(acc[i][0].x, acc[i][0].y, acc[i][1].x, acc[i][1].y);
                float4 hi = make_float4(acc[i][2].x, acc[i][2].y, acc[i][3].x, acc[i][3].y);
                float4* plo = red4 + d * 16 + pj;
                float4* phi = red4 + d * 16 + 8 + pj;
                if (w != 0) {
                    const float4 a = *plo; const float4 b = *phi;
                    lo.x += a.x; lo.y += a.y; lo.z += a.z; lo.w += a.w;
                    hi.x += b.x; hi.y += b.y; hi.z += b.z; hi.w += b.w;
                }
                *plo = lo; *phi = hi;
            }
            if (vq == 0) {
                float* p = kred + dq * 8;
#pragma unroll
                for (int j = 0; j < 4; ++j) {
                    f2 s = ksum2[j];
                    if (w != 0) { s.x += p[2*j]; s.y += p[2*j+1]; }
                    p[2*j] = s.x; p[2*j+1] = s.y;
                }
            }
        }
    }
    __syncthreads();

    // coalesced store of the block's partial (undo the chunk swizzle)
    float4* dst = (float4*)(ws + (size_t)blockIdx.x * WSPH);
    for (int i = t; i < 1024; i += 256) {
        const int row = i >> 4, j = i & 15;
        const int pj = (((j & 7) ^ (row >> 3)) | (j & 8));
        dst[i] = red4[row * 16 + pj];
    }
    if (t < 16)
        dst[1024 + t] = ((const float4*)kred)[t];
}

// ---------------- Kernel 1r: reduce 32 partials per head -> final KV+Ksum ----
__global__ __launch_bounds__(256) void la_reduce_kernel(
    const float* __restrict__ ws, float* __restrict__ kvout)
{
    const int h   = blockIdx.x / 5;
    const int seg = blockIdx.x % 5;
    const int t   = threadIdx.x;
    if (t >= 208) return;
    const int i4 = seg * 208 + t;

    const float4* base = (const float4*)(ws + (size_t)h * K1CH * WSPH) + i4;
    float4 acc = make_float4(0.f, 0.f, 0.f, 0.f);
#pragma unroll 8
    for (int p = 0; p < K1CH; ++p) {
        const float4 x = base[(size_t)p * WSPH4];
        acc.x += x.x; acc.y += x.y; acc.z += x.z; acc.w += x.w;
    }
    ((float4*)(kvout + (size_t)h * WSPH))[i4] = acc;
}

// ---------------- Kernel 2: out = (Qf @ KV) / (Qf·Ksum + eps) -----------------
// 1024 blocks (bh, tile of 128 rows), 256 threads.
__global__ __launch_bounds__(256) void la_out_kernel(
    const float* __restrict__ Qg, const float* __restrict__ kvin,
    float* __restrict__ out)
{
    __shared__ float qlds[128 * ST2];    // 43008 B, pitch 84
    __shared__ float kvlds[DDIM * DDIM];
    __shared__ float ksl[DDIM];
    __shared__ float zs[128];

    const int t    = threadIdx.x;
    const int bh   = blockIdx.x >> 5;
    const int tile = blockIdx.x & 31;
    const size_t base = (size_t)bh * LSEQ * DDIM + (size_t)tile * 128 * DDIM;
    const float4* Qb4 = (const float4*)(Qg + base);

    // stage Qf (fmap once) at pitch ST2
#pragma unroll
    for (int i = 0; i < 8; ++i) {
        const int o = t + i * 256;           // f4 index in 128x16
        const float4 q = fmap4(Qb4[o]);
        const int row = o >> 4, c4 = o & 15;
        *(float4*)(qlds + row * ST2 + c4 * 4) = q;
    }
    // stage KV + Ksum
    const float4* wsrc = (const float4*)(kvin + (size_t)bh * WSPH);
    for (int i = t; i < WSPH4; i += 256) {
        const float4 x = wsrc[i];
        if (i < 1024) ((float4*)kvlds)[i] = x;
        else          ((float4*)ksl)[i - 1024] = x;
    }
    __syncthreads();

    // den pass: 2 threads per row
    {
        const int row  = t >> 1;
        const int half = t & 1;
        float s = 0.0f;
#pragma unroll
        for (int j = 0; j < 8; ++j) {
            const float4 q  = *(const float4*)(qlds + row * ST2 + half * 32 + j * 4);
            const float4 ks = *(const float4*)(ksl + half * 32 + j * 4);
            s += q.x * ks.x + q.y * ks.y + q.z * ks.z + q.w * ks.w;
        }
        s += __shfl_xor(s, 1);
        if (half == 0) zs[row] = 1.0f / (s + 1e-6f);
    }
    __syncthreads();

    // compute: lane owns rows {rg, rg+32, rg+64, rg+96} x cols {vq*4..+3, 32+vq*4..+3}
    const int rg = t >> 3;
    const int vq = t & 7;
    f2 acc[4][4];
#pragma unroll
    for (int k = 0; k < 4; ++k)
#pragma unroll
        for (int j = 0; j < 4; ++j) acc[k][j] = (f2)(0.0f);

#pragma unroll 1
    for (int d4 = 0; d4 < 16; ++d4) {
        f2 kv[4][4];
#pragma unroll
        for (int i = 0; i < 4; ++i) {
            const float4 a = *(const float4*)(kvlds + (d4 * 4 + i) * DDIM + vq * 4);
            const float4 b = *(const float4*)(kvlds + (d4 * 4 + i) * DDIM + 32 + vq * 4);
            kv[i][0] = (f2){a.x, a.y}; kv[i][1] = (f2){a.z, a.w};
            kv[i][2] = (f2){b.x, b.y}; kv[i][3] = (f2){b.z, b.w};
        }
#pragma unroll
        for (int k = 0; k < 4; ++k) {
            const float4 q = *(const float4*)(qlds + (rg + 32 * k) * ST2 + d4 * 4);
            const float qa[4] = {q.x, q.y, q.z, q.w};
#pragma unroll
            for (int i = 0; i < 4; ++i) {
                const f2 qd = {qa[i], qa[i]};
#pragma unroll
                for (int j = 0; j < 4; ++j)
                    acc[k][j] = pkfma(qd, kv[i][j], acc[k][j]);
            }
        }
    }

#pragma unroll
    for (int k = 0; k < 4; ++k) {
        const int row = rg + 32 * k;
        const float z = zs[row];
        float* orow = out + base + (size_t)row * DDIM;
        const float4 lo = make_float4(acc[k][0].x * z, acc[k][0].y * z,
                                      acc[k][1].x * z, acc[k][1].y * z);
        const float4 hi = make_float4(acc[k][2].x * z, acc[k][2].y * z,
                                      acc[k][3].x * z, acc[k][3].y * z);
        *(float4*)(orow + vq * 4) = lo;
        *(float4*)(orow + 32 + vq * 4) = hi;
    }
}

extern "C" void kernel_launch(void* const* d_in, const int* in_sizes, int n_in,
                              void* d_out, int out_size, void* d_ws, size_t ws_size,
                              hipStream_t stream) {
    const float* q = (const float*)d_in[0];
    const float* k = (const float*)d_in[1];
    const float* v = (const float*)d_in[2];
    float* o  = (float*)d_out;
    float* ws = (float*)d_ws;
    float* kvfinal = ws + (size_t)NHEAD * K1CH * WSPH;

    hipLaunchKernelGGL(la_kv_kernel, dim3(NHEAD * K1CH), dim3(256), 0, stream,
                       k, v, ws);
    hipLaunchKernelGGL(la_reduce_kernel, dim3(NHEAD * 5), dim3(256), 0, stream,
                       ws, kvfinal);
    hipLaunchKernelGGL(la_out_kernel, dim3(NHEAD * 32), dim3(256), 0, stream,
                       q, kvfinal, o);
}